// Round 1
// baseline (863.839 us; speedup 1.0000x reference)
//
#include <hip/hip_runtime.h>

#define B_    2048
#define LAT   16
#define C_    23
#define HID0  16
#define HID1  32
#define NOUT  4000
#define EPS_  1e-5f
#define SLOPE 0.2f
#define J_    (C_*HID0)   // 368
#define CO_   (C_*HID1)   // 736

typedef __bf16 bf16x8 __attribute__((ext_vector_type(8)));
typedef __bf16 bf16x4 __attribute__((ext_vector_type(4)));
typedef float  f32x4  __attribute__((ext_vector_type(4)));

__device__ __forceinline__ float leaky(float v) { return v >= 0.f ? v : SLOPE * v; }

// ---------------- K1: h_pre = x @ W1^T + b1, plus per-column sum/sumsq ----------------
// grid = 23 * 8 (c, b-range of 256), block = 256 (16 j x 16 rowgroups)
__global__ void k1(const float* __restrict__ x, const float* __restrict__ W1,
                   const float* __restrict__ b1, float* __restrict__ hpre,
                   float* __restrict__ gsum1, float* __restrict__ gss1) {
    int c  = blockIdx.x >> 3;
    int b0 = (blockIdx.x & 7) * 256;
    __shared__ float xs[256][17];
    __shared__ float wls[16][17];
    __shared__ float red[2][16][16];
    int t = threadIdx.x;
    #pragma unroll
    for (int s = 0; s < 4; ++s) {
        int chunk = t + 256 * s;            // 1024 float4 chunks
        int row = chunk >> 2, off = (chunk & 3) * 4;
        float4 v = *(const float4*)(x + (size_t)(b0 + row) * LAT + off);
        xs[row][off + 0] = v.x; xs[row][off + 1] = v.y;
        xs[row][off + 2] = v.z; xs[row][off + 3] = v.w;
    }
    if (t < 64) {
        int row = t >> 2, off = (t & 3) * 4;
        float4 v = *(const float4*)(W1 + (size_t)(c * 16 + row) * LAT + off);
        wls[row][off + 0] = v.x; wls[row][off + 1] = v.y;
        wls[row][off + 2] = v.z; wls[row][off + 3] = v.w;
    }
    __syncthreads();
    int jl = t & 15, rg = t >> 4;
    float w[16];
    #pragma unroll
    for (int i = 0; i < 16; ++i) w[i] = wls[jl][i];
    float bb = b1[c * 16 + jl];
    float sum = 0.f, ss = 0.f;
    for (int s = 0; s < 16; ++s) {
        int row = rg + 16 * s;
        float acc = bb;
        #pragma unroll
        for (int i = 0; i < 16; ++i) acc += xs[row][i] * w[i];
        hpre[(size_t)(b0 + row) * J_ + c * 16 + jl] = acc;
        sum += acc; ss += acc * acc;
    }
    red[0][rg][jl] = sum; red[1][rg][jl] = ss;
    __syncthreads();
    if (t < 16) {
        float s0 = 0.f, s1 = 0.f;
        #pragma unroll
        for (int r = 0; r < 16; ++r) { s0 += red[0][r][t]; s1 += red[1][r][t]; }
        atomicAdd(gsum1 + c * 16 + t, s0);
        atomicAdd(gss1  + c * 16 + t, s1);
    }
}

// ---------------- K1b: fold BN1 stats into affine a1,c1 ----------------
__global__ void k1b(const float* __restrict__ g1, const float* __restrict__ be1,
                    const float* __restrict__ gsum1, const float* __restrict__ gss1,
                    float* __restrict__ a1, float* __restrict__ c1) {
    int j = threadIdx.x;
    if (j < J_) {
        float mean = gsum1[j] * (1.f / B_);
        float var  = gss1[j] * (1.f / B_) - mean * mean;
        float a = g1[j] * rsqrtf(var + EPS_);
        a1[j] = a;
        c1[j] = be1[j] - mean * a;
    }
}

// ---------------- K2: z_pre = leaky(bn(h)) chunks @ W0^T + b0, plus stats ----------------
// grid = 23 * 32 (c, b-tile of 64), block = 256 (32 o x 8 b-subgroups)
__global__ void k2(const float* __restrict__ hpre, const float* __restrict__ a1,
                   const float* __restrict__ c1, const float* __restrict__ W0,
                   const float* __restrict__ b0, float* __restrict__ zpre,
                   float* __restrict__ gsum0, float* __restrict__ gss0) {
    int c = blockIdx.x >> 5;
    int base_b = (blockIdx.x & 31) * 64;
    __shared__ float ha[64][17];
    __shared__ float red[2][8][32];
    int t = threadIdx.x;
    {
        int row = t >> 2, io = (t & 3) * 4;
        float4 v  = *(const float4*)(hpre + (size_t)(base_b + row) * J_ + c * 16 + io);
        float4 av = *(const float4*)(a1 + c * 16 + io);
        float4 cv = *(const float4*)(c1 + c * 16 + io);
        ha[row][io + 0] = leaky(av.x * v.x + cv.x);
        ha[row][io + 1] = leaky(av.y * v.y + cv.y);
        ha[row][io + 2] = leaky(av.z * v.z + cv.z);
        ha[row][io + 3] = leaky(av.w * v.w + cv.w);
    }
    __syncthreads();
    int o = t & 31, bsub = t >> 5;
    float w0r[16];
    const float* wp = W0 + ((size_t)c * HID1 + o) * HID0;
    #pragma unroll
    for (int i = 0; i < 16; ++i) w0r[i] = wp[i];
    float bb = b0[c * HID1 + o];
    float sum = 0.f, ss = 0.f;
    for (int s = 0; s < 8; ++s) {
        int row = bsub * 8 + s;
        float acc = bb;
        #pragma unroll
        for (int i = 0; i < 16; ++i) acc += ha[row][i] * w0r[i];
        zpre[((size_t)(base_b + row) * C_ + c) * HID1 + o] = acc;
        sum += acc; ss += acc * acc;
    }
    red[0][bsub][o] = sum; red[1][bsub][o] = ss;
    __syncthreads();
    if (t < 32) {
        float s0 = 0.f, s1 = 0.f;
        #pragma unroll
        for (int r = 0; r < 8; ++r) { s0 += red[0][r][t]; s1 += red[1][r][t]; }
        atomicAdd(gsum0 + c * HID1 + t, s0);
        atomicAdd(gss0  + c * HID1 + t, s1);
    }
}

// ---------------- K2b: fold BN0 stats into affine a0,c0 ----------------
__global__ void k2b(const float* __restrict__ g0, const float* __restrict__ bb0,
                    const float* __restrict__ gsum0, const float* __restrict__ gss0,
                    float* __restrict__ a0, float* __restrict__ c0) {
    int j = threadIdx.x;
    if (j < CO_) {
        float mean = gsum0[j] * (1.f / B_);
        float var  = gss0[j] * (1.f / B_) - mean * mean;
        float a = g0[j] * rsqrtf(var + EPS_);
        a0[j] = a;
        c0[j] = bb0[j] - mean * a;
    }
}

// ---------------- K2c: zb = bf16(leaky(bn(z_pre))), layout [b][c][k] ----------------
// grid = 1472 * 256 threads, 4 elems each (2048*23*32 = 1,507,328)
__global__ void k2c(const float* __restrict__ zpre, const float* __restrict__ a0,
                    const float* __restrict__ c0, __bf16* __restrict__ zb) {
    int tid = blockIdx.x * 256 + threadIdx.x;
    size_t base = (size_t)tid * 4;
    float4 v = *(const float4*)(zpre + base);
    int ck = (int)(base % CO_);     // c*32 + k, 4-aligned
    float4 av = *(const float4*)(a0 + ck);
    float4 cv = *(const float4*)(c0 + ck);
    bf16x4 o;
    o[0] = (__bf16)leaky(av.x * v.x + cv.x);
    o[1] = (__bf16)leaky(av.y * v.y + cv.y);
    o[2] = (__bf16)leaky(av.z * v.z + cv.z);
    o[3] = (__bf16)leaky(av.w * v.w + cv.w);
    *(bf16x4*)(zb + base) = o;
}

// ---------------- K2d: w2b = bf16(W2) ----------------
// grid = 2875 * 256 threads, 4 elems each (23*4000*32 = 2,944,000)
__global__ void k2d(const float* __restrict__ W2, __bf16* __restrict__ w2b) {
    int tid = blockIdx.x * 256 + threadIdx.x;
    size_t base = (size_t)tid * 4;
    float4 v = *(const float4*)(W2 + base);
    bf16x4 o;
    o[0] = (__bf16)v.x; o[1] = (__bf16)v.y; o[2] = (__bf16)v.z; o[3] = (__bf16)v.w;
    *(bf16x4*)(w2b + base) = o;
}

// ---------------- K3: out = sigmoid(z @ W2^T + b2), MFMA bf16, write-bound ----------------
// grid = 23 * 50 * 2 (c, o-tile of 80, b-half), block = 256 (4 waves)
// wave handles 16 n-rows? no: wave covers b-range of 256 (16 iters x 16 b), 80 o (5 MFMA n-tiles)
__global__ __launch_bounds__(256) void k3(const __bf16* __restrict__ zb,
                                          const __bf16* __restrict__ w2b,
                                          const float* __restrict__ b2,
                                          float* __restrict__ out) {
    int bi  = blockIdx.x;
    int c   = bi / 100;
    int rem = bi % 100;
    int ot  = rem >> 1;
    int bh  = rem & 1;
    int t = threadIdx.x;
    int w = t >> 6, l = t & 63;
    int lo = l & 15, qu = l >> 4;
    int o0 = ot * 80;

    // B fragments: B[n=lo][k=qu*8+j] from w2b[c][o][k] — held in registers for whole b-loop
    bf16x8 bf[5];
    float  b2v[5];
    #pragma unroll
    for (int j = 0; j < 5; ++j) {
        int o = o0 + j * 16 + lo;
        bf[j]  = *(const bf16x8*)(w2b + ((size_t)c * NOUT + o) * HID1 + qu * 8);
        b2v[j] = b2[(size_t)c * NOUT + o];
    }

    int bbase = bh * 1024 + w * 256;
    for (int it = 0; it < 16; ++it) {
        int b = bbase + it * 16;
        // A fragment: A[m=lo][k=qu*8+j] from zb[b+lo][c][k] — 16 contiguous bytes
        bf16x8 af = *(const bf16x8*)(zb + ((size_t)(b + lo) * C_ + c) * HID1 + qu * 8);
        f32x4 acc[5];
        #pragma unroll
        for (int j = 0; j < 5; ++j) {
            f32x4 z4 = {0.f, 0.f, 0.f, 0.f};
            acc[j] = __builtin_amdgcn_mfma_f32_16x16x32_bf16(af, bf[j], z4, 0, 0, 0);
        }
        // epilogue: D[row=qu*4+r][col=lo] per tile j
        #pragma unroll
        for (int j = 0; j < 5; ++j) {
            #pragma unroll
            for (int r = 0; r < 4; ++r) {
                float v = acc[j][r] + b2v[j];
                float e = __builtin_amdgcn_exp2f(v * -1.44269504088896f);
                float sg = __builtin_amdgcn_rcpf(1.0f + e);
                int row = b + qu * 4 + r;
                out[(size_t)row * (C_ * NOUT) + (size_t)c * NOUT + o0 + j * 16 + lo] = sg;
            }
        }
    }
}

extern "C" void kernel_launch(void* const* d_in, const int* in_sizes, int n_in,
                              void* d_out, int out_size, void* d_ws, size_t ws_size,
                              hipStream_t stream) {
    const float* x   = (const float*)d_in[0];
    const float* W1  = (const float*)d_in[1];
    const float* b1  = (const float*)d_in[2];
    const float* g1  = (const float*)d_in[3];
    const float* be1 = (const float*)d_in[4];
    const float* W0  = (const float*)d_in[5];
    const float* b0  = (const float*)d_in[6];
    const float* g0  = (const float*)d_in[7];
    const float* bb0 = (const float*)d_in[8];
    const float* W2  = (const float*)d_in[9];
    const float* b2  = (const float*)d_in[10];
    float* out = (float*)d_out;

    float* f = (float*)d_ws;
    float* f_h     = f;                       // 2048*368 = 753,664
    float* f_stats = f_h + (size_t)B_ * J_;   // 2208 floats: gsum1[368] gss1[368] gsum0[736] gss0[736]
    float* gsum1 = f_stats;
    float* gss1  = f_stats + 368;
    float* gsum0 = f_stats + 736;
    float* gss0  = f_stats + 1472;
    float* f_aff = f_stats + 2208;            // a1[368] c1[368] a0[736] c0[736]
    float* a1 = f_aff;
    float* c1 = f_aff + 368;
    float* a0 = f_aff + 736;
    float* c0 = f_aff + 1472;
    float* f_z = f_aff + 2208;                // 2048*736 = 1,507,328
    __bf16* zb  = (__bf16*)(f_z + (size_t)B_ * CO_);
    __bf16* w2b = zb + (size_t)B_ * CO_;      // 2,944,000 bf16

    hipMemsetAsync(f_stats, 0, 2208 * sizeof(float), stream);
    k1 <<<C_ * 8,   256, 0, stream>>>(x, W1, b1, f_h, gsum1, gss1);
    k1b<<<1,        384, 0, stream>>>(g1, be1, gsum1, gss1, a1, c1);
    k2 <<<C_ * 32,  256, 0, stream>>>(f_h, a1, c1, W0, b0, f_z, gsum0, gss0);
    k2b<<<1,        768, 0, stream>>>(g0, bb0, gsum0, gss0, a0, c0);
    k2c<<<1472,     256, 0, stream>>>(f_z, a0, c0, zb);
    k2d<<<2875,     256, 0, stream>>>(W2, w2b);
    k3 <<<C_ * 100, 256, 0, stream>>>(zb, w2b, b2, out);
}